// Round 5
// baseline (212.732 us; speedup 1.0000x reference)
//
#include <hip/hip_runtime.h>
#include <math.h>

// DecoderCell fused kernel — Round 5: RT=32/NT=256, 40,448 B LDS -> 4
// blocks/CU (16 waves) for cross-block phase overlap. Same single-pass
// weight reads + merged r/z accumulators as R4. All GEMMs bf16 MFMA.
//
// LDS pool (bytes):
//   [0,20992)      sA  [32][328] con_input      ; sGo [32][216] after B2
//   [20992,34816)  sR2 [32][136] con_state (in-place) ; sGn [32][216] after B5
//   [34816,40448)  sR3 [32][88]  gen_input(20+pad) + factor(64)

#define NT 256
#define RT 32
#define XD 272
#define HD 420

typedef unsigned short ushort_t;
typedef __attribute__((ext_vector_type(8))) short bf8;
typedef __attribute__((ext_vector_type(4))) float f4;
typedef __attribute__((ext_vector_type(4))) unsigned short us4;

// ws layout (bf16 element offsets)
#define WS_W1 0         // con_w_ih [384][320]
#define WS_W2 122880    // con_w_hh [384][128]
#define WS_W3 172032    // gen_w_ih [608][32]  (K 20->32 pad, rows 600-607 zero)
#define WS_W4 191488    // gen_w_hh [608][224] (K 200->224 pad, rows 600-607 zero)
#define WS_W5 327680    // normed fac_w [64][224] (K pad zero)

#define STA 328
#define STG 216
#define STH 136
#define STR3 88

#define O_A   0
#define O_R2  20992
#define O_GN  20992
#define O_R3  34816
#define POOLB 40448

__device__ __forceinline__ ushort_t f2bf(float f) {
  union { float f; unsigned u; } v; v.f = f;
  unsigned r = v.u + 0x7FFFu + ((v.u >> 16) & 1u);
  return (ushort_t)(r >> 16);
}
__device__ __forceinline__ float bf2f(ushort_t u) {
  union { unsigned u; float f; } v; v.u = ((unsigned)u) << 16; return v.f;
}
__device__ __forceinline__ us4 f2bf4(f4 v) {
  us4 b; b.x = f2bf(v.x); b.y = f2bf(v.y); b.z = f2bf(v.z); b.w = f2bf(v.w); return b;
}
__device__ __forceinline__ f4 bf2f4(us4 b) {
  f4 v; v.x = bf2f(b.x); v.y = bf2f(b.y); v.z = bf2f(b.z); v.w = bf2f(b.w); return v;
}
__device__ __forceinline__ float sigf(float x) { return 1.0f / (1.0f + __expf(-x)); }
__device__ __forceinline__ float tanhf_(float x) { float e = __expf(2.0f * x); return 1.0f - 2.0f / (e + 1.0f); }

#define MFMA(a, b, c) __builtin_amdgcn_mfma_f32_16x16x32_bf16((a), (b), (c), 0, 0, 0)

__global__ void prep_w(const float* __restrict__ cw1, const float* __restrict__ cw2,
                       const float* __restrict__ gw3, const float* __restrict__ gw4,
                       ushort_t* __restrict__ ws) {
  int tid = blockIdx.x * blockDim.x + threadIdx.x;
  int np = gridDim.x * blockDim.x;
  for (int i = tid; i < 384 * 320; i += np) ws[WS_W1 + i] = f2bf(cw1[i]);
  for (int i = tid; i < 384 * 128; i += np) ws[WS_W2 + i] = f2bf(cw2[i]);
  for (int i = tid; i < 608 * 32; i += np) {
    int n = i >> 5, k = i & 31;
    ws[WS_W3 + i] = (n < 600 && k < 20) ? f2bf(gw3[n * 20 + k]) : (ushort_t)0;
  }
  for (int i = tid; i < 608 * 224; i += np) {
    int n = i / 224, k = i - n * 224;
    ws[WS_W4 + i] = (n < 600 && k < 200) ? f2bf(gw4[n * 200 + k]) : (ushort_t)0;
  }
}

__global__ void prep_fac(const float* __restrict__ fw, ushort_t* __restrict__ ws) {
  int n = blockIdx.x;   // 64 rows
  int l = threadIdx.x;  // 64 lanes
  float ss = 0.f;
  for (int k = l; k < 200; k += 64) { float v = fw[n * 200 + k]; ss = fmaf(v, v, ss); }
  for (int off = 32; off; off >>= 1) ss += __shfl_down(ss, off, 64);
  ss = __shfl(ss, 0, 64);
  float inv = 1.0f / fmaxf(sqrtf(ss), 1e-12f);
  for (int k = l; k < 224; k += 64)
    ws[WS_W5 + n * 224 + k] = (k < 200) ? f2bf(fw[n * 200 + k] * inv) : (ushort_t)0;
}

__global__ __launch_bounds__(NT, 4) void decoder_kernel(
    const float* __restrict__ x, const float* __restrict__ h0, const float* __restrict__ eps,
    const float* __restrict__ gen_b_ih, const float* __restrict__ gen_b_hh,
    const float* __restrict__ con_b_ih, const float* __restrict__ con_b_hh,
    const float* __restrict__ co_w, const float* __restrict__ co_b,
    const ushort_t* __restrict__ ws, float* __restrict__ out)
{
  __shared__ __align__(16) unsigned char spool[POOLB];
  ushort_t* sA  = (ushort_t*)(spool + O_A);    // con_input [32][328]
  ushort_t* sGo = (ushort_t*)(spool + O_A);    // gen_state_old [32][216]
  ushort_t* sR2 = (ushort_t*)(spool + O_R2);   // con_state(128)+mean(4)+std(4)
  ushort_t* sGn = (ushort_t*)(spool + O_GN);   // gen_state_new [32][216]
  ushort_t* sR3 = (ushort_t*)(spool + O_R3);   // gen_input(20+12p)+factor(64)

  const int tid = threadIdx.x;
  const int rbase = blockIdx.x * RT;
  const int lane = tid & 63;
  const int w = tid >> 6;             // wave 0..3
  const int bn = lane & 15;           // frag row/col within 16
  const int kq = (lane >> 4) << 3;    // k offset of quarter-wave
  const int qrow = (lane >> 4) << 2;  // C/D row offset of quarter-wave

  // ---------------- ph1: stage con_input, con_state, ext; zero gi pad
  #pragma unroll
  for (int it = 0; it < 8; ++it) {  // x[:,0:256] -> sA
    int idx = tid + it * NT;
    int r = idx >> 6, c4 = (idx & 63) << 2;
    f4 v = *(const f4*)&x[(size_t)(rbase + r) * XD + c4];
    *(us4*)&sA[r * STA + c4] = f2bf4(v);
  }
  if (tid < 128) {  // x[:,256:272] -> sR3 cols 4..20 (gen_input ext)
    int r = tid >> 2, e = (tid & 3) << 2;
    f4 v = *(const f4*)&x[(size_t)(rbase + r) * XD + 256 + e];
    *(us4*)&sR3[r * STR3 + 4 + e] = f2bf4(v);
  }
  #pragma unroll
  for (int it = 0; it < 4; ++it) {  // h0[:,200:328] -> sR2 (con_state_old)
    int idx = tid + it * NT;
    int r = idx >> 5, c4 = (idx & 31) << 2;
    f4 v = *(const f4*)&h0[(size_t)(rbase + r) * HD + 200 + c4];
    *(us4*)&sR2[r * STH + c4] = f2bf4(v);
  }
  #pragma unroll
  for (int it = 0; it < 2; ++it) {  // h0[:,356:420] -> sA cols 256..320
    int idx = tid + it * NT;
    int r = idx >> 4, c4 = (idx & 15) << 2;
    f4 v = *(const f4*)&h0[(size_t)(rbase + r) * HD + 356 + c4];
    *(us4*)&sA[r * STA + 256 + c4] = f2bf4(v);
  }
  if (tid < 96) {  // zero sR3 cols 20..32 (gi K-pad)
    int r = tid / 3, q = (tid - (tid / 3) * 3) << 2;
    us4 z = {0, 0, 0, 0};
    *(us4*)&sR3[r * STR3 + 20 + q] = z;
  }
  __syncthreads();  // B1

  // ---------------- ph2: con GEMMs, 2 col-tiles/wave, single weight pass
  f4 aR[2][2], aZ[2][2], aN[2][2], aHN[2][2];  // [ti][ri]
  #pragma unroll
  for (int ti = 0; ti < 2; ++ti)
    #pragma unroll
    for (int ri = 0; ri < 2; ++ri) {
      aR[ti][ri] = (f4){0.f, 0.f, 0.f, 0.f};
      aZ[ti][ri] = (f4){0.f, 0.f, 0.f, 0.f};
      aN[ti][ri] = (f4){0.f, 0.f, 0.f, 0.f};
      aHN[ti][ri] = (f4){0.f, 0.f, 0.f, 0.f};
    }
  #pragma unroll
  for (int ti = 0; ti < 2; ++ti) {
    const int col = ((w + 4 * ti) << 4) + bn;  // 0..127
    const ushort_t* W2 = ws + WS_W2;
    #pragma unroll
    for (int k0 = 0; k0 < 128; k0 += 32) {
      bf8 br = *(const bf8*)&W2[(size_t)(col) * 128 + k0 + kq];
      bf8 bz = *(const bf8*)&W2[(size_t)(128 + col) * 128 + k0 + kq];
      bf8 bm = *(const bf8*)&W2[(size_t)(256 + col) * 128 + k0 + kq];
      #pragma unroll
      for (int ri = 0; ri < 2; ++ri) {
        bf8 a = *(const bf8*)&sR2[(ri * 16 + bn) * STH + k0 + kq];
        aR[ti][ri] = MFMA(a, br, aR[ti][ri]);
        aZ[ti][ri] = MFMA(a, bz, aZ[ti][ri]);
        aHN[ti][ri] = MFMA(a, bm, aHN[ti][ri]);
      }
    }
    const ushort_t* W1 = ws + WS_W1;
    #pragma unroll
    for (int k0 = 0; k0 < 320; k0 += 32) {
      bf8 br = *(const bf8*)&W1[(size_t)(col) * 320 + k0 + kq];
      bf8 bz = *(const bf8*)&W1[(size_t)(128 + col) * 320 + k0 + kq];
      bf8 bm = *(const bf8*)&W1[(size_t)(256 + col) * 320 + k0 + kq];
      #pragma unroll
      for (int ri = 0; ri < 2; ++ri) {
        bf8 a = *(const bf8*)&sA[(ri * 16 + bn) * STA + k0 + kq];
        aR[ti][ri] = MFMA(a, br, aR[ti][ri]);
        aZ[ti][ri] = MFMA(a, bz, aZ[ti][ri]);
        aN[ti][ri] = MFMA(a, bm, aN[ti][ri]);
      }
    }
  }
  __syncthreads();  // B2 (sA + sR2 frag reads done)

  // ---------------- ph3: stage gen_state_old (aliases sA) || con elementwise
  for (int idx = tid; idx < 32 * 54; idx += NT) {
    int r = idx / 54, u = idx - (idx / 54) * 54;
    if (u < 50) {
      f4 v = *(const f4*)&h0[(size_t)(rbase + r) * HD + (u << 2)];
      *(us4*)&sGo[r * STG + (u << 2)] = f2bf4(v);
    } else {
      us4 z = {0, 0, 0, 0};
      *(us4*)&sGo[r * STG + 200 + ((u - 50) << 2)] = z;  // gh K-pad
    }
  }
  #pragma unroll
  for (int ti = 0; ti < 2; ++ti) {
    const int col = ((w + 4 * ti) << 4) + bn;
    float brr = con_b_ih[col] + con_b_hh[col];
    float brz = con_b_ih[128 + col] + con_b_hh[128 + col];
    float bin = con_b_ih[256 + col], bhn = con_b_hh[256 + col];
    #pragma unroll
    for (int ri = 0; ri < 2; ++ri) {
      #pragma unroll
      for (int j = 0; j < 4; ++j) {
        int row = ri * 16 + qrow + j;
        float hold = bf2f(sR2[row * STH + col]);
        float rr = sigf(aR[ti][ri][j] + brr);
        float zz = sigf(aZ[ti][ri][j] + brz);
        float nn = tanhf_(aN[ti][ri][j] + bin + rr * (aHN[ti][ri][j] + bhn));
        float hv = (1.f - zz) * nn + zz * hold;
        hv = fminf(fmaxf(hv, -5.f), 5.f);
        sR2[row * STH + col] = f2bf(hv);  // own (row,col) only: no race
      }
    }
  }
  __syncthreads();  // B3

  // ---------------- ph4: co linear + reparam (f32 VALU; 32 rows x 8 cols)
  {
    int crow = tid >> 3, cn = tid & 7;
    float acc = co_b[cn];
    #pragma unroll 8
    for (int k0 = 0; k0 < 128; k0 += 4) {
      f4 hv = bf2f4(*(const us4*)&sR2[crow * STH + k0]);
      f4 wv = *(const f4*)&co_w[cn * 128 + k0];
      acc = fmaf(hv.x, wv.x, acc);
      acc = fmaf(hv.y, wv.y, acc);
      acc = fmaf(hv.z, wv.z, acc);
      acc = fmaf(hv.w, wv.w, acc);
    }
    float lv = __shfl(acc, lane + 4, 64);  // partner lane holds logvar
    if (cn < 4) {
      float stdv = __expf(0.5f * lv);
      float ov = fmaf(stdv, eps[(size_t)(rbase + crow) * 4 + cn], acc);
      sR2[crow * STH + 128 + cn] = f2bf(acc);
      sR2[crow * STH + 132 + cn] = f2bf(stdv);
      sR3[crow * STR3 + cn] = f2bf(ov);
    }
  }
  __syncthreads();  // B4

  // ---------------- ph5: flush out[:,200:336) from sR2 (coalesced span)
  for (int idx = tid; idx < 32 * 34; idx += NT) {
    int r = idx / 34, c4 = (idx - (idx / 34) * 34) << 2;
    f4 v = bf2f4(*(const us4*)&sR2[r * STH + c4]);
    *(f4*)&out[(size_t)(rbase + r) * HD + 200 + c4] = v;
  }
  __syncthreads();  // B5 (sR2 dead; sGn aliases it)

  // ---------------- ph6: gen GRU (13 col-tiles over 4 waves)
  if (tid < 128) {  // zero sGn K-pad cols 200..216
    int r = tid >> 2, q = (tid & 3) << 2;
    us4 z = {0, 0, 0, 0};
    *(us4*)&sGn[r * STG + 200 + q] = z;
  }
  {
    const ushort_t* W3 = ws + WS_W3;
    const ushort_t* W4 = ws + WS_W4;
    for (int t = w; t < 13; t += 4) {
      int c = (t << 4) + bn;  // output column (valid < 200)
      f4 gR[2], gZ[2], gN[2], gHN[2];
      #pragma unroll
      for (int ri = 0; ri < 2; ++ri) {
        gR[ri] = (f4){0.f, 0.f, 0.f, 0.f};
        gZ[ri] = (f4){0.f, 0.f, 0.f, 0.f};
        gN[ri] = (f4){0.f, 0.f, 0.f, 0.f};
        gHN[ri] = (f4){0.f, 0.f, 0.f, 0.f};
      }
      {  // gi (K=32, A = gen_input in sR3)
        bf8 br = *(const bf8*)&W3[(size_t)(c) * 32 + kq];
        bf8 bz = *(const bf8*)&W3[(size_t)(200 + c) * 32 + kq];
        bf8 bm = *(const bf8*)&W3[(size_t)(400 + c) * 32 + kq];
        #pragma unroll
        for (int ri = 0; ri < 2; ++ri) {
          bf8 a = *(const bf8*)&sR3[(ri * 16 + bn) * STR3 + kq];
          gR[ri] = MFMA(a, br, gR[ri]);
          gZ[ri] = MFMA(a, bz, gZ[ri]);
          gN[ri] = MFMA(a, bm, gN[ri]);
        }
      }
      #pragma unroll
      for (int k0 = 0; k0 < 224; k0 += 32) {  // gh (K=200 padded)
        bf8 br = *(const bf8*)&W4[(size_t)(c) * 224 + k0 + kq];
        bf8 bz = *(const bf8*)&W4[(size_t)(200 + c) * 224 + k0 + kq];
        bf8 bm = *(const bf8*)&W4[(size_t)(400 + c) * 224 + k0 + kq];
        #pragma unroll
        for (int ri = 0; ri < 2; ++ri) {
          bf8 a = *(const bf8*)&sGo[(ri * 16 + bn) * STG + k0 + kq];
          gR[ri] = MFMA(a, br, gR[ri]);
          gZ[ri] = MFMA(a, bz, gZ[ri]);
          gHN[ri] = MFMA(a, bm, gHN[ri]);
        }
      }
      if (c < 200) {
        float brr = gen_b_ih[c] + gen_b_hh[c];
        float brz = gen_b_ih[200 + c] + gen_b_hh[200 + c];
        float bin = gen_b_ih[400 + c], bhn = gen_b_hh[400 + c];
        #pragma unroll
        for (int ri = 0; ri < 2; ++ri) {
          #pragma unroll
          for (int j = 0; j < 4; ++j) {
            int row = ri * 16 + qrow + j;
            float hold = bf2f(sGo[row * STG + c]);
            float rr = sigf(gR[ri][j] + brr);
            float zz = sigf(gZ[ri][j] + brz);
            float nn = tanhf_(gN[ri][j] + bin + rr * (gHN[ri][j] + bhn));
            float hv = (1.f - zz) * nn + zz * hold;
            hv = fminf(fmaxf(hv, -5.f), 5.f);
            sGn[row * STG + c] = f2bf(hv);
          }
        }
      }
    }
  }
  __syncthreads();  // B6

  // ---------------- ph7: factor = gen_state_new @ normed_fac^T -> sR3[20:84)
  {
    const ushort_t* W5 = ws + WS_W5;
    int ri = w & 1;
    #pragma unroll
    for (int cc = 0; cc < 2; ++cc) {
      int ct = (w >> 1) + 2 * cc;  // 0..3
      f4 acc = (f4){0.f, 0.f, 0.f, 0.f};
      #pragma unroll
      for (int k0 = 0; k0 < 224; k0 += 32) {
        bf8 b = *(const bf8*)&W5[(size_t)((ct << 4) + bn) * 224 + k0 + kq];
        bf8 a = *(const bf8*)&sGn[(ri * 16 + bn) * STG + k0 + kq];
        acc = MFMA(a, b, acc);
      }
      #pragma unroll
      for (int j = 0; j < 4; ++j) {
        int row = ri * 16 + qrow + j;
        sR3[row * STR3 + 20 + (ct << 4) + bn] = f2bf(acc[j]);
      }
    }
  }
  __syncthreads();  // B7

  // ---------------- ph8: final flush out[:,0:200) + out[:,336:420)
  for (int idx = tid; idx < 32 * 71; idx += NT) {
    int r = idx / 71, u = idx - (idx / 71) * 71;
    if (u < 50) {
      f4 v = bf2f4(*(const us4*)&sGn[r * STG + (u << 2)]);
      *(f4*)&out[(size_t)(rbase + r) * HD + (u << 2)] = v;
    } else {
      int u2 = u - 50;
      f4 v = bf2f4(*(const us4*)&sR3[r * STR3 + (u2 << 2)]);
      *(f4*)&out[(size_t)(rbase + r) * HD + 336 + (u2 << 2)] = v;
    }
  }
}

extern "C" void kernel_launch(void* const* d_in, const int* in_sizes, int n_in,
                              void* d_out, int out_size, void* d_ws, size_t ws_size,
                              hipStream_t stream) {
  const float* x        = (const float*)d_in[0];
  const float* h0       = (const float*)d_in[1];
  const float* eps      = (const float*)d_in[2];
  const float* gen_w_ih = (const float*)d_in[3];
  const float* gen_w_hh = (const float*)d_in[4];
  const float* gen_b_ih = (const float*)d_in[5];
  const float* gen_b_hh = (const float*)d_in[6];
  const float* con_w_ih = (const float*)d_in[7];
  const float* con_w_hh = (const float*)d_in[8];
  const float* con_b_ih = (const float*)d_in[9];
  const float* con_b_hh = (const float*)d_in[10];
  const float* co_w     = (const float*)d_in[11];
  const float* co_b     = (const float*)d_in[12];
  const float* fac_w    = (const float*)d_in[13];
  float* out = (float*)d_out;
  ushort_t* ws = (ushort_t*)d_ws;

  hipLaunchKernelGGL(prep_w, dim3(256), dim3(512), 0, stream,
                     con_w_ih, con_w_hh, gen_w_ih, gen_w_hh, ws);
  hipLaunchKernelGGL(prep_fac, dim3(64), dim3(64), 0, stream, fac_w, ws);

  int nrows = in_sizes[2] / 4;  // eps is (B,4)
  int grid = nrows / RT;        // 2048
  hipLaunchKernelGGL(decoder_kernel, dim3(grid), dim3(NT), 0, stream,
                     x, h0, eps, gen_b_ih, gen_b_hh, con_b_ih, con_b_hh,
                     co_w, co_b, ws, out);
}

// Round 6
// 199.411 us; speedup vs baseline: 1.0668x; 1.0668x over previous
//
#include <hip/hip_runtime.h>
#include <math.h>

// DecoderCell fused kernel — Round 6: R4 shape (RT=64/NT=512) + explicit
// B-fragment register prefetch (all weight loads issued before the MFMA
// chain of each col-tile; W1 in 2 batches to bound VGPR) + register-carried
// async stage of h0[0:200) (issued ph1, written to LDS ph3). Theory: the
// ~160us of unhidden stall is L2 weight-load latency with MLP~1; forcing
// 12-30 loads in flight removes it. __launch_bounds__(512,2) -> 256 VGPR cap.

#define NT 512
#define RT 64
#define XD 272
#define HD 420

typedef unsigned short ushort_t;
typedef __attribute__((ext_vector_type(8))) short bf8;
typedef __attribute__((ext_vector_type(4))) float f4;
typedef __attribute__((ext_vector_type(4))) unsigned short us4;

// ws layout (bf16 element offsets)
#define WS_W1 0         // con_w_ih [384][320]
#define WS_W2 122880    // con_w_hh [384][128]
#define WS_W3 172032    // gen_w_ih [608][32]  (K 20->32 pad, rows 600-607 zero)
#define WS_W4 191488    // gen_w_hh [608][224] (K 200->224 pad, rows 600-607 zero)
#define WS_W5 327680    // normed fac_w [64][224] (K pad zero)

#define STA 328
#define STG 216
#define STH 136
#define STR3 88

#define O_A   0
#define O_R2  41984
#define O_GN  41984
#define O_R3  69632
#define POOLB 80896

__device__ __forceinline__ ushort_t f2bf(float f) {
  union { float f; unsigned u; } v; v.f = f;
  unsigned r = v.u + 0x7FFFu + ((v.u >> 16) & 1u);
  return (ushort_t)(r >> 16);
}
__device__ __forceinline__ float bf2f(ushort_t u) {
  union { unsigned u; float f; } v; v.u = ((unsigned)u) << 16; return v.f;
}
__device__ __forceinline__ us4 f2bf4(f4 v) {
  us4 b; b.x = f2bf(v.x); b.y = f2bf(v.y); b.z = f2bf(v.z); b.w = f2bf(v.w); return b;
}
__device__ __forceinline__ f4 bf2f4(us4 b) {
  f4 v; v.x = bf2f(b.x); v.y = bf2f(b.y); v.z = bf2f(b.z); v.w = bf2f(b.w); return v;
}
__device__ __forceinline__ float sigf(float x) { return 1.0f / (1.0f + __expf(-x)); }
__device__ __forceinline__ float tanhf_(float x) { float e = __expf(2.0f * x); return 1.0f - 2.0f / (e + 1.0f); }

#define MFMA(a, b, c) __builtin_amdgcn_mfma_f32_16x16x32_bf16((a), (b), (c), 0, 0, 0)

__global__ void prep_w(const float* __restrict__ cw1, const float* __restrict__ cw2,
                       const float* __restrict__ gw3, const float* __restrict__ gw4,
                       ushort_t* __restrict__ ws) {
  int tid = blockIdx.x * blockDim.x + threadIdx.x;
  int np = gridDim.x * blockDim.x;
  for (int i = tid; i < 384 * 320; i += np) ws[WS_W1 + i] = f2bf(cw1[i]);
  for (int i = tid; i < 384 * 128; i += np) ws[WS_W2 + i] = f2bf(cw2[i]);
  for (int i = tid; i < 608 * 32; i += np) {
    int n = i >> 5, k = i & 31;
    ws[WS_W3 + i] = (n < 600 && k < 20) ? f2bf(gw3[n * 20 + k]) : (ushort_t)0;
  }
  for (int i = tid; i < 608 * 224; i += np) {
    int n = i / 224, k = i - n * 224;
    ws[WS_W4 + i] = (n < 600 && k < 200) ? f2bf(gw4[n * 200 + k]) : (ushort_t)0;
  }
}

__global__ void prep_fac(const float* __restrict__ fw, ushort_t* __restrict__ ws) {
  int n = blockIdx.x;   // 64 rows
  int l = threadIdx.x;  // 64 lanes
  float ss = 0.f;
  for (int k = l; k < 200; k += 64) { float v = fw[n * 200 + k]; ss = fmaf(v, v, ss); }
  for (int off = 32; off; off >>= 1) ss += __shfl_down(ss, off, 64);
  ss = __shfl(ss, 0, 64);
  float inv = 1.0f / fmaxf(sqrtf(ss), 1e-12f);
  for (int k = l; k < 224; k += 64)
    ws[WS_W5 + n * 224 + k] = (k < 200) ? f2bf(fw[n * 200 + k] * inv) : (ushort_t)0;
}

__global__ __launch_bounds__(NT, 2) void decoder_kernel(
    const float* __restrict__ x, const float* __restrict__ h0, const float* __restrict__ eps,
    const float* __restrict__ gen_b_ih, const float* __restrict__ gen_b_hh,
    const float* __restrict__ con_b_ih, const float* __restrict__ con_b_hh,
    const float* __restrict__ co_w, const float* __restrict__ co_b,
    const ushort_t* __restrict__ ws, float* __restrict__ out)
{
  __shared__ __align__(16) unsigned char spool[POOLB];
  ushort_t* sA  = (ushort_t*)(spool + O_A);    // con_input [64][328]
  ushort_t* sGo = (ushort_t*)(spool + O_A);    // gen_state_old [64][216]
  ushort_t* sR2 = (ushort_t*)(spool + O_R2);   // con_state(128)+mean(4)+std(4)
  ushort_t* sGn = (ushort_t*)(spool + O_GN);   // gen_state_new [64][216]
  ushort_t* sR3 = (ushort_t*)(spool + O_R3);   // gen_input(20+12p)+factor(64)

  const int tid = threadIdx.x;
  const int rbase = blockIdx.x * RT;
  const int lane = tid & 63;
  const int w = tid >> 6;
  const int bn = lane & 15;           // frag row/col within 16
  const int kq = (lane >> 4) << 3;    // k offset of quarter-wave
  const int qrow = (lane >> 4) << 2;  // C/D row offset of quarter-wave

  // ---------------- ph1: stage con tiles; issue gen_state h0 loads to regs
  f4 hcar[7];                          // h0[:,0:200) carried in registers
  #pragma unroll
  for (int it = 0; it < 7; ++it) {
    int idx = tid + it * NT;
    if (idx < 64 * 50) {
      int r = idx / 50, u = idx - (idx / 50) * 50;
      hcar[it] = *(const f4*)&h0[(size_t)(rbase + r) * HD + (u << 2)];
    }
  }
  #pragma unroll
  for (int it = 0; it < 8; ++it) {  // x[:,0:256] -> sA
    int idx = tid + it * NT;
    int r = idx >> 6, c4 = (idx & 63) << 2;
    f4 v = *(const f4*)&x[(size_t)(rbase + r) * XD + c4];
    *(us4*)&sA[r * STA + c4] = f2bf4(v);
  }
  if (tid < 256) {  // x[:,256:272] -> sR3 cols 4..20 (gen_input ext)
    int r = tid >> 2, e = (tid & 3) << 2;
    f4 v = *(const f4*)&x[(size_t)(rbase + r) * XD + 256 + e];
    *(us4*)&sR3[r * STR3 + 4 + e] = f2bf4(v);
  }
  #pragma unroll
  for (int it = 0; it < 4; ++it) {  // h0[:,200:328] -> sR2 (con_state_old)
    int idx = tid + it * NT;
    int r = idx >> 5, c4 = (idx & 31) << 2;
    f4 v = *(const f4*)&h0[(size_t)(rbase + r) * HD + 200 + c4];
    *(us4*)&sR2[r * STH + c4] = f2bf4(v);
  }
  #pragma unroll
  for (int it = 0; it < 2; ++it) {  // h0[:,356:420] -> sA cols 256..320
    int idx = tid + it * NT;
    int r = idx >> 4, c4 = (idx & 15) << 2;
    f4 v = *(const f4*)&h0[(size_t)(rbase + r) * HD + 356 + c4];
    *(us4*)&sA[r * STA + 256 + c4] = f2bf4(v);
  }
  if (tid < 192) {  // zero sR3 cols 20..32 (gi K-pad)
    int r = tid / 3, q = (tid - (tid / 3) * 3) << 2;
    us4 z = {0, 0, 0, 0};
    *(us4*)&sR3[r * STR3 + 20 + q] = z;
  }
  __syncthreads();  // B1

  const int col = (w << 4) + bn;  // wave's con output column (0..127)

  // ---------------- ph2: con GEMMs with explicit B-fragment prefetch
  f4 aR[4], aZ[4], aN[4], aHN[4];
  #pragma unroll
  for (int ri = 0; ri < 4; ++ri) {
    aR[ri] = (f4){0.f, 0.f, 0.f, 0.f};
    aZ[ri] = (f4){0.f, 0.f, 0.f, 0.f};
    aN[ri] = (f4){0.f, 0.f, 0.f, 0.f};
    aHN[ri] = (f4){0.f, 0.f, 0.f, 0.f};
  }
  {
    const ushort_t* W2 = ws + WS_W2;
    const ushort_t* W1 = ws + WS_W1;
    // prefetch all 12 W2 frags + batch A of W1 (15 frags)
    bf8 w2f[4][3], w1a[5][3], w1b[5][3];
    #pragma unroll
    for (int k = 0; k < 4; ++k) {
      w2f[k][0] = *(const bf8*)&W2[(size_t)(col) * 128 + k * 32 + kq];
      w2f[k][1] = *(const bf8*)&W2[(size_t)(128 + col) * 128 + k * 32 + kq];
      w2f[k][2] = *(const bf8*)&W2[(size_t)(256 + col) * 128 + k * 32 + kq];
    }
    #pragma unroll
    for (int k = 0; k < 5; ++k) {
      w1a[k][0] = *(const bf8*)&W1[(size_t)(col) * 320 + k * 32 + kq];
      w1a[k][1] = *(const bf8*)&W1[(size_t)(128 + col) * 320 + k * 32 + kq];
      w1a[k][2] = *(const bf8*)&W1[(size_t)(256 + col) * 320 + k * 32 + kq];
    }
    float bi0 = con_b_ih[col], bi1 = con_b_ih[128 + col], bi2 = con_b_ih[256 + col];
    float bh0 = con_b_hh[col], bh1 = con_b_hh[128 + col], bh2 = con_b_hh[256 + col];
    // compute gh while gi batch A is in flight
    #pragma unroll
    for (int k = 0; k < 4; ++k) {
      #pragma unroll
      for (int ri = 0; ri < 4; ++ri) {
        bf8 a = *(const bf8*)&sR2[(ri * 16 + bn) * STH + k * 32 + kq];
        aR[ri] = MFMA(a, w2f[k][0], aR[ri]);
        aZ[ri] = MFMA(a, w2f[k][1], aZ[ri]);
        aHN[ri] = MFMA(a, w2f[k][2], aHN[ri]);
      }
    }
    // issue batch B, compute batch A
    #pragma unroll
    for (int k = 0; k < 5; ++k) {
      w1b[k][0] = *(const bf8*)&W1[(size_t)(col) * 320 + (k + 5) * 32 + kq];
      w1b[k][1] = *(const bf8*)&W1[(size_t)(128 + col) * 320 + (k + 5) * 32 + kq];
      w1b[k][2] = *(const bf8*)&W1[(size_t)(256 + col) * 320 + (k + 5) * 32 + kq];
    }
    #pragma unroll
    for (int k = 0; k < 5; ++k) {
      #pragma unroll
      for (int ri = 0; ri < 4; ++ri) {
        bf8 a = *(const bf8*)&sA[(ri * 16 + bn) * STA + k * 32 + kq];
        aR[ri] = MFMA(a, w1a[k][0], aR[ri]);
        aZ[ri] = MFMA(a, w1a[k][1], aZ[ri]);
        aN[ri] = MFMA(a, w1a[k][2], aN[ri]);
      }
    }
    #pragma unroll
    for (int k = 0; k < 5; ++k) {
      #pragma unroll
      for (int ri = 0; ri < 4; ++ri) {
        bf8 a = *(const bf8*)&sA[(ri * 16 + bn) * STA + (k + 5) * 32 + kq];
        aR[ri] = MFMA(a, w1b[k][0], aR[ri]);
        aZ[ri] = MFMA(a, w1b[k][1], aZ[ri]);
        aN[ri] = MFMA(a, w1b[k][2], aN[ri]);
      }
    }
    __syncthreads();  // B2 (sA + sR2 frag reads done)

    // ---------------- ph3: write carried gen_state to sGo || con elementwise
    #pragma unroll
    for (int it = 0; it < 7; ++it) {
      int idx = tid + it * NT;
      if (idx < 64 * 50) {
        int r = idx / 50, u = idx - (idx / 50) * 50;
        *(us4*)&sGo[r * STG + (u << 2)] = f2bf4(hcar[it]);
      }
    }
    if (tid < 256) {  // zero sGo K-pad cols 200..216
      int r = tid >> 2, q = (tid & 3) << 2;
      us4 z = {0, 0, 0, 0};
      *(us4*)&sGo[r * STG + 200 + q] = z;
    }
    {
      float brr = bi0 + bh0;
      float brz = bi1 + bh1;
      #pragma unroll
      for (int ri = 0; ri < 4; ++ri) {
        #pragma unroll
        for (int j = 0; j < 4; ++j) {
          int row = ri * 16 + qrow + j;
          float hold = bf2f(sR2[row * STH + col]);
          float rr = sigf(aR[ri][j] + brr);
          float zz = sigf(aZ[ri][j] + brz);
          float nn = tanhf_(aN[ri][j] + bi2 + rr * (aHN[ri][j] + bh2));
          float hv = (1.f - zz) * nn + zz * hold;
          hv = fminf(fmaxf(hv, -5.f), 5.f);
          sR2[row * STH + col] = f2bf(hv);  // own (row,col) only: no race
        }
      }
    }
  }
  __syncthreads();  // B3

  // ---------------- ph4: co linear + reparam (f32 VALU)
  {
    int crow = tid >> 3, cn = tid & 7;
    float acc = co_b[cn];
    #pragma unroll 8
    for (int k0 = 0; k0 < 128; k0 += 4) {
      f4 hv = bf2f4(*(const us4*)&sR2[crow * STH + k0]);
      f4 wv = *(const f4*)&co_w[cn * 128 + k0];
      acc = fmaf(hv.x, wv.x, acc);
      acc = fmaf(hv.y, wv.y, acc);
      acc = fmaf(hv.z, wv.z, acc);
      acc = fmaf(hv.w, wv.w, acc);
    }
    float lv = __shfl(acc, lane + 4, 64);  // partner lane holds logvar
    if (cn < 4) {
      float stdv = __expf(0.5f * lv);
      float ov = fmaf(stdv, eps[(size_t)(rbase + crow) * 4 + cn], acc);
      sR2[crow * STH + 128 + cn] = f2bf(acc);
      sR2[crow * STH + 132 + cn] = f2bf(stdv);
      sR3[crow * STR3 + cn] = f2bf(ov);
    }
  }
  __syncthreads();  // B4

  // ---------------- ph5: flush out[:,200:336) from sR2 (coalesced span)
  for (int idx = tid; idx < 64 * 34; idx += NT) {
    int r = idx / 34, c4 = (idx - (idx / 34) * 34) << 2;
    f4 v = bf2f4(*(const us4*)&sR2[r * STH + c4]);
    *(f4*)&out[(size_t)(rbase + r) * HD + 200 + c4] = v;
  }
  __syncthreads();  // B5 (sR2 dead; sGn aliases it)

  // ---------------- ph6: gen GRU (13 col-tiles over 8 waves), prefetched
  if (tid < 256) {  // zero sGn K-pad cols 200..216
    int r = tid >> 2, q = (tid & 3) << 2;
    us4 z = {0, 0, 0, 0};
    *(us4*)&sGn[r * STG + 200 + q] = z;
  }
  {
    const ushort_t* W3 = ws + WS_W3;
    const ushort_t* W4 = ws + WS_W4;
    for (int t = w; t < 13; t += 8) {
      int c = (t << 4) + bn;  // output column (valid < 200)
      bf8 w3f[3], w4f[7][3];
      w3f[0] = *(const bf8*)&W3[(size_t)(c) * 32 + kq];
      w3f[1] = *(const bf8*)&W3[(size_t)(200 + c) * 32 + kq];
      w3f[2] = *(const bf8*)&W3[(size_t)(400 + c) * 32 + kq];
      #pragma unroll
      for (int k = 0; k < 7; ++k) {
        w4f[k][0] = *(const bf8*)&W4[(size_t)(c) * 224 + k * 32 + kq];
        w4f[k][1] = *(const bf8*)&W4[(size_t)(200 + c) * 224 + k * 32 + kq];
        w4f[k][2] = *(const bf8*)&W4[(size_t)(400 + c) * 224 + k * 32 + kq];
      }
      float bi0 = 0.f, bi1 = 0.f, bi2 = 0.f, bh0 = 0.f, bh1 = 0.f, bh2 = 0.f;
      if (c < 200) {
        bi0 = gen_b_ih[c]; bi1 = gen_b_ih[200 + c]; bi2 = gen_b_ih[400 + c];
        bh0 = gen_b_hh[c]; bh1 = gen_b_hh[200 + c]; bh2 = gen_b_hh[400 + c];
      }
      f4 gR[4], gZ[4], gN[4], gHN[4];
      #pragma unroll
      for (int ri = 0; ri < 4; ++ri) {
        gR[ri] = (f4){0.f, 0.f, 0.f, 0.f};
        gZ[ri] = (f4){0.f, 0.f, 0.f, 0.f};
        gN[ri] = (f4){0.f, 0.f, 0.f, 0.f};
        gHN[ri] = (f4){0.f, 0.f, 0.f, 0.f};
      }
      #pragma unroll
      for (int ri = 0; ri < 4; ++ri) {  // gi (K=32)
        bf8 a = *(const bf8*)&sR3[(ri * 16 + bn) * STR3 + kq];
        gR[ri] = MFMA(a, w3f[0], gR[ri]);
        gZ[ri] = MFMA(a, w3f[1], gZ[ri]);
        gN[ri] = MFMA(a, w3f[2], gN[ri]);
      }
      #pragma unroll
      for (int k = 0; k < 7; ++k) {  // gh (K=224 padded)
        #pragma unroll
        for (int ri = 0; ri < 4; ++ri) {
          bf8 a = *(const bf8*)&sGo[(ri * 16 + bn) * STG + k * 32 + kq];
          gR[ri] = MFMA(a, w4f[k][0], gR[ri]);
          gZ[ri] = MFMA(a, w4f[k][1], gZ[ri]);
          gHN[ri] = MFMA(a, w4f[k][2], gHN[ri]);
        }
      }
      if (c < 200) {
        float brr = bi0 + bh0;
        float brz = bi1 + bh1;
        #pragma unroll
        for (int ri = 0; ri < 4; ++ri) {
          #pragma unroll
          for (int j = 0; j < 4; ++j) {
            int row = ri * 16 + qrow + j;
            float hold = bf2f(sGo[row * STG + c]);
            float rr = sigf(gR[ri][j] + brr);
            float zz = sigf(gZ[ri][j] + brz);
            float nn = tanhf_(gN[ri][j] + bi2 + rr * (gHN[ri][j] + bh2));
            float hv = (1.f - zz) * nn + zz * hold;
            hv = fminf(fmaxf(hv, -5.f), 5.f);
            sGn[row * STG + c] = f2bf(hv);
          }
        }
      }
    }
  }
  __syncthreads();  // B6

  // ---------------- ph7: factor = gen_state_new @ normed_fac^T, prefetched
  {
    const ushort_t* W5 = ws + WS_W5;
    int ri = w & 3;
    #pragma unroll
    for (int cc = 0; cc < 2; ++cc) {
      int ct = (w >> 2) + 2 * cc;  // 0..3
      bf8 w5f[7];
      #pragma unroll
      for (int k = 0; k < 7; ++k)
        w5f[k] = *(const bf8*)&W5[(size_t)((ct << 4) + bn) * 224 + k * 32 + kq];
      f4 acc = (f4){0.f, 0.f, 0.f, 0.f};
      #pragma unroll
      for (int k = 0; k < 7; ++k) {
        bf8 a = *(const bf8*)&sGn[(ri * 16 + bn) * STG + k * 32 + kq];
        acc = MFMA(a, w5f[k], acc);
      }
      #pragma unroll
      for (int j = 0; j < 4; ++j) {
        int row = ri * 16 + qrow + j;
        sR3[row * STR3 + 20 + (ct << 4) + bn] = f2bf(acc[j]);
      }
    }
  }
  __syncthreads();  // B7

  // ---------------- ph8: final flush out[:,0:200) + out[:,336:420)
  for (int idx = tid; idx < 64 * 71; idx += NT) {
    int r = idx / 71, u = idx - (idx / 71) * 71;
    if (u < 50) {
      f4 v = bf2f4(*(const us4*)&sGn[r * STG + (u << 2)]);
      *(f4*)&out[(size_t)(rbase + r) * HD + (u << 2)] = v;
    } else {
      int u2 = u - 50;
      f4 v = bf2f4(*(const us4*)&sR3[r * STR3 + (u2 << 2)]);
      *(f4*)&out[(size_t)(rbase + r) * HD + 336 + (u2 << 2)] = v;
    }
  }
}

extern "C" void kernel_launch(void* const* d_in, const int* in_sizes, int n_in,
                              void* d_out, int out_size, void* d_ws, size_t ws_size,
                              hipStream_t stream) {
  const float* x        = (const float*)d_in[0];
  const float* h0       = (const float*)d_in[1];
  const float* eps      = (const float*)d_in[2];
  const float* gen_w_ih = (const float*)d_in[3];
  const float* gen_w_hh = (const float*)d_in[4];
  const float* gen_b_ih = (const float*)d_in[5];
  const float* gen_b_hh = (const float*)d_in[6];
  const float* con_w_ih = (const float*)d_in[7];
  const float* con_w_hh = (const float*)d_in[8];
  const float* con_b_ih = (const float*)d_in[9];
  const float* con_b_hh = (const float*)d_in[10];
  const float* co_w     = (const float*)d_in[11];
  const float* co_b     = (const float*)d_in[12];
  const float* fac_w    = (const float*)d_in[13];
  float* out = (float*)d_out;
  ushort_t* ws = (ushort_t*)d_ws;

  hipLaunchKernelGGL(prep_w, dim3(256), dim3(512), 0, stream,
                     con_w_ih, con_w_hh, gen_w_ih, gen_w_hh, ws);
  hipLaunchKernelGGL(prep_fac, dim3(64), dim3(64), 0, stream, fac_w, ws);

  int nrows = in_sizes[2] / 4;  // eps is (B,4)
  int grid = nrows / RT;        // 1024
  hipLaunchKernelGGL(decoder_kernel, dim3(grid), dim3(NT), 0, stream,
                     x, h0, eps, gen_b_ih, gen_b_hh, con_b_ih, con_b_hh,
                     co_w, co_b, ws, out);
}

// Round 7
// 175.900 us; speedup vs baseline: 1.2094x; 1.1337x over previous
//
#include <hip/hip_runtime.h>
#include <math.h>

// DecoderCell fused kernel — Round 7: RT=128/NT=512 (8 row-tiles per wave).
// Rationale: R4-R6 showed ~200us invariant to occupancy/prefetch => shared
// resource = per-chip weight re-fetch (L2 thrashed by streaming; each block
// pulls 684KB from L3). RT=128 halves total weight traffic and gives each
// B-fragment 24 dependent MFMAs (~120cyc) so weight-load latency self-hides.
// LDS 141,312B, 1 block/CU. Accumulators 32xf4 = 128 VGPR; weight prefetch
// batched to stay under the 256-VGPR cap of __launch_bounds__(512,2).

#define NT 512
#define RT 128
#define XD 272
#define HD 420

typedef unsigned short ushort_t;
typedef __attribute__((ext_vector_type(8))) short bf8;
typedef __attribute__((ext_vector_type(4))) float f4;
typedef __attribute__((ext_vector_type(4))) unsigned short us4;

// ws layout (bf16 element offsets)
#define WS_W1 0         // con_w_ih [384][320]
#define WS_W2 122880    // con_w_hh [384][128]
#define WS_W3 172032    // gen_w_ih [608][32]  (K 20->32 pad, rows 600-607 zero)
#define WS_W4 191488    // gen_w_hh [608][224] (K 200->224 pad, rows 600-607 zero)
#define WS_W5 327680    // normed fac_w [64][224] (K pad zero)

#define STA 328
#define STG 216
#define STH 136
#define STR3 88

#define O_A   0        // sA [128][328] = 83,968 ; later sGo [128][216]=55,296
#define O_GN  55296    // sGn [128][216] = 55,296 (over dead sA tail + sR2)
#define O_R2  83968    // sR2 [128][136] = 34,816
#define O_R3  118784   // sR3 [128][88]  = 22,528
#define POOLB 141312

__device__ __forceinline__ ushort_t f2bf(float f) {
  union { float f; unsigned u; } v; v.f = f;
  unsigned r = v.u + 0x7FFFu + ((v.u >> 16) & 1u);
  return (ushort_t)(r >> 16);
}
__device__ __forceinline__ float bf2f(ushort_t u) {
  union { unsigned u; float f; } v; v.u = ((unsigned)u) << 16; return v.f;
}
__device__ __forceinline__ us4 f2bf4(f4 v) {
  us4 b; b.x = f2bf(v.x); b.y = f2bf(v.y); b.z = f2bf(v.z); b.w = f2bf(v.w); return b;
}
__device__ __forceinline__ f4 bf2f4(us4 b) {
  f4 v; v.x = bf2f(b.x); v.y = bf2f(b.y); v.z = bf2f(b.z); v.w = bf2f(b.w); return v;
}
__device__ __forceinline__ float sigf(float x) { return 1.0f / (1.0f + __expf(-x)); }
__device__ __forceinline__ float tanhf_(float x) { float e = __expf(2.0f * x); return 1.0f - 2.0f / (e + 1.0f); }

#define MFMA(a, b, c) __builtin_amdgcn_mfma_f32_16x16x32_bf16((a), (b), (c), 0, 0, 0)

__global__ void prep_w(const float* __restrict__ cw1, const float* __restrict__ cw2,
                       const float* __restrict__ gw3, const float* __restrict__ gw4,
                       ushort_t* __restrict__ ws) {
  int tid = blockIdx.x * blockDim.x + threadIdx.x;
  int np = gridDim.x * blockDim.x;
  for (int i = tid; i < 384 * 320; i += np) ws[WS_W1 + i] = f2bf(cw1[i]);
  for (int i = tid; i < 384 * 128; i += np) ws[WS_W2 + i] = f2bf(cw2[i]);
  for (int i = tid; i < 608 * 32; i += np) {
    int n = i >> 5, k = i & 31;
    ws[WS_W3 + i] = (n < 600 && k < 20) ? f2bf(gw3[n * 20 + k]) : (ushort_t)0;
  }
  for (int i = tid; i < 608 * 224; i += np) {
    int n = i / 224, k = i - n * 224;
    ws[WS_W4 + i] = (n < 600 && k < 200) ? f2bf(gw4[n * 200 + k]) : (ushort_t)0;
  }
}

__global__ void prep_fac(const float* __restrict__ fw, ushort_t* __restrict__ ws) {
  int n = blockIdx.x;   // 64 rows
  int l = threadIdx.x;  // 64 lanes
  float ss = 0.f;
  for (int k = l; k < 200; k += 64) { float v = fw[n * 200 + k]; ss = fmaf(v, v, ss); }
  for (int off = 32; off; off >>= 1) ss += __shfl_down(ss, off, 64);
  ss = __shfl(ss, 0, 64);
  float inv = 1.0f / fmaxf(sqrtf(ss), 1e-12f);
  for (int k = l; k < 224; k += 64)
    ws[WS_W5 + n * 224 + k] = (k < 200) ? f2bf(fw[n * 200 + k] * inv) : (ushort_t)0;
}

__global__ __launch_bounds__(NT, 2) void decoder_kernel(
    const float* __restrict__ x, const float* __restrict__ h0, const float* __restrict__ eps,
    const float* __restrict__ gen_b_ih, const float* __restrict__ gen_b_hh,
    const float* __restrict__ con_b_ih, const float* __restrict__ con_b_hh,
    const float* __restrict__ co_w, const float* __restrict__ co_b,
    const ushort_t* __restrict__ ws, float* __restrict__ out)
{
  __shared__ __align__(16) unsigned char spool[POOLB];
  ushort_t* sA  = (ushort_t*)(spool + O_A);    // con_input [128][328]
  ushort_t* sGo = (ushort_t*)(spool + O_A);    // gen_state_old [128][216]
  ushort_t* sGn = (ushort_t*)(spool + O_GN);   // gen_state_new [128][216]
  ushort_t* sR2 = (ushort_t*)(spool + O_R2);   // con_state(128)+mean(4)+std(4)
  ushort_t* sR3 = (ushort_t*)(spool + O_R3);   // gen_input(20+12p)+factor(64)

  const int tid = threadIdx.x;
  const int rbase = blockIdx.x * RT;
  const int lane = tid & 63;
  const int w = tid >> 6;
  const int bn = lane & 15;           // frag row/col within 16
  const int kq = (lane >> 4) << 3;    // k offset of quarter-wave
  const int qrow = (lane >> 4) << 2;  // C/D row offset of quarter-wave

  // ---------------- ph1: stage con_input, con_state, factor, ext
  #pragma unroll
  for (int it = 0; it < 16; ++it) {  // x[:,0:256] -> sA
    int idx = tid + it * NT;
    int r = idx >> 6, c4 = (idx & 63) << 2;
    f4 v = *(const f4*)&x[(size_t)(rbase + r) * XD + c4];
    *(us4*)&sA[r * STA + c4] = f2bf4(v);
  }
  {  // x[:,256:272] -> sR3 cols 4..20 (gen_input ext)
    int r = tid >> 2, e = (tid & 3) << 2;
    f4 v = *(const f4*)&x[(size_t)(rbase + r) * XD + 256 + e];
    *(us4*)&sR3[r * STR3 + 4 + e] = f2bf4(v);
  }
  #pragma unroll
  for (int it = 0; it < 8; ++it) {  // h0[:,200:328] -> sR2 (con_state_old)
    int idx = tid + it * NT;
    int r = idx >> 5, c4 = (idx & 31) << 2;
    f4 v = *(const f4*)&h0[(size_t)(rbase + r) * HD + 200 + c4];
    *(us4*)&sR2[r * STH + c4] = f2bf4(v);
  }
  #pragma unroll
  for (int it = 0; it < 4; ++it) {  // h0[:,356:420] -> sA cols 256..320
    int idx = tid + it * NT;
    int r = idx >> 4, c4 = (idx & 15) << 2;
    f4 v = *(const f4*)&h0[(size_t)(rbase + r) * HD + 356 + c4];
    *(us4*)&sA[r * STA + 256 + c4] = f2bf4(v);
  }
  if (tid < 384) {  // zero sR3 cols 20..32 (gi K-pad)
    int r = tid / 3, q = (tid - (tid / 3) * 3) << 2;
    us4 z = {0, 0, 0, 0};
    *(us4*)&sR3[r * STR3 + 20 + q] = z;
  }
  __syncthreads();  // B1

  const int col = (w << 4) + bn;  // wave's con output column (0..127)

  // ---------------- ph2: con GEMMs (8 row-tiles/wave), batched prefetch
  f4 aR[8], aZ[8], aN[8], aHN[8];
  #pragma unroll
  for (int ri = 0; ri < 8; ++ri) {
    aR[ri] = (f4){0.f, 0.f, 0.f, 0.f};
    aZ[ri] = (f4){0.f, 0.f, 0.f, 0.f};
    aN[ri] = (f4){0.f, 0.f, 0.f, 0.f};
    aHN[ri] = (f4){0.f, 0.f, 0.f, 0.f};
  }
  {
    const ushort_t* W2 = ws + WS_W2;
    const ushort_t* W1 = ws + WS_W1;
    bf8 w2f[4][3], w1a[5][3];
    #pragma unroll
    for (int k = 0; k < 4; ++k) {
      w2f[k][0] = *(const bf8*)&W2[(size_t)(col) * 128 + k * 32 + kq];
      w2f[k][1] = *(const bf8*)&W2[(size_t)(128 + col) * 128 + k * 32 + kq];
      w2f[k][2] = *(const bf8*)&W2[(size_t)(256 + col) * 128 + k * 32 + kq];
    }
    #pragma unroll
    for (int k = 0; k < 5; ++k) {
      w1a[k][0] = *(const bf8*)&W1[(size_t)(col) * 320 + k * 32 + kq];
      w1a[k][1] = *(const bf8*)&W1[(size_t)(128 + col) * 320 + k * 32 + kq];
      w1a[k][2] = *(const bf8*)&W1[(size_t)(256 + col) * 320 + k * 32 + kq];
    }
    #pragma unroll
    for (int k = 0; k < 4; ++k) {  // gh (K=128)
      #pragma unroll
      for (int ri = 0; ri < 8; ++ri) {
        bf8 a = *(const bf8*)&sR2[(ri * 16 + bn) * STH + k * 32 + kq];
        aR[ri] = MFMA(a, w2f[k][0], aR[ri]);
        aZ[ri] = MFMA(a, w2f[k][1], aZ[ri]);
        aHN[ri] = MFMA(a, w2f[k][2], aHN[ri]);
      }
    }
    bf8 w1b[5][3];
    #pragma unroll
    for (int k = 0; k < 5; ++k) {
      w1b[k][0] = *(const bf8*)&W1[(size_t)(col) * 320 + (k + 5) * 32 + kq];
      w1b[k][1] = *(const bf8*)&W1[(size_t)(128 + col) * 320 + (k + 5) * 32 + kq];
      w1b[k][2] = *(const bf8*)&W1[(size_t)(256 + col) * 320 + (k + 5) * 32 + kq];
    }
    #pragma unroll
    for (int k = 0; k < 5; ++k) {  // gi batch A
      #pragma unroll
      for (int ri = 0; ri < 8; ++ri) {
        bf8 a = *(const bf8*)&sA[(ri * 16 + bn) * STA + k * 32 + kq];
        aR[ri] = MFMA(a, w1a[k][0], aR[ri]);
        aZ[ri] = MFMA(a, w1a[k][1], aZ[ri]);
        aN[ri] = MFMA(a, w1a[k][2], aN[ri]);
      }
    }
    #pragma unroll
    for (int k = 0; k < 5; ++k) {  // gi batch B
      #pragma unroll
      for (int ri = 0; ri < 8; ++ri) {
        bf8 a = *(const bf8*)&sA[(ri * 16 + bn) * STA + (k + 5) * 32 + kq];
        aR[ri] = MFMA(a, w1b[k][0], aR[ri]);
        aZ[ri] = MFMA(a, w1b[k][1], aZ[ri]);
        aN[ri] = MFMA(a, w1b[k][2], aN[ri]);
      }
    }
  }
  __syncthreads();  // B2 (sA + sR2 frag reads done)

  // ---------------- ph3: stage gen_state_old (over dead sA) || elementwise
  for (int idx = tid; idx < 128 * 54; idx += NT) {
    int r = idx / 54, u = idx - (idx / 54) * 54;
    if (u < 50) {
      f4 v = *(const f4*)&h0[(size_t)(rbase + r) * HD + (u << 2)];
      *(us4*)&sGo[r * STG + (u << 2)] = f2bf4(v);
    } else {
      us4 z = {0, 0, 0, 0};
      *(us4*)&sGo[r * STG + 200 + ((u - 50) << 2)] = z;  // gh K-pad
    }
  }
  {
    float brr = con_b_ih[col] + con_b_hh[col];
    float brz = con_b_ih[128 + col] + con_b_hh[128 + col];
    float bin = con_b_ih[256 + col], bhn = con_b_hh[256 + col];
    #pragma unroll
    for (int ri = 0; ri < 8; ++ri) {
      #pragma unroll
      for (int j = 0; j < 4; ++j) {
        int row = ri * 16 + qrow + j;
        float hold = bf2f(sR2[row * STH + col]);
        float rr = sigf(aR[ri][j] + brr);
        float zz = sigf(aZ[ri][j] + brz);
        float nn = tanhf_(aN[ri][j] + bin + rr * (aHN[ri][j] + bhn));
        float hv = (1.f - zz) * nn + zz * hold;
        hv = fminf(fmaxf(hv, -5.f), 5.f);
        sR2[row * STH + col] = f2bf(hv);  // own (row,col) only: no race
      }
    }
  }
  __syncthreads();  // B3

  // ---------------- ph4: co linear + reparam (f32 VALU; 128 rows x 8 cols)
  {
    int cn = tid & 7;
    #pragma unroll
    for (int half = 0; half < 2; ++half) {
      int crow = (tid >> 3) + half * 64;
      float acc = co_b[cn];
      #pragma unroll 8
      for (int k0 = 0; k0 < 128; k0 += 4) {
        f4 hv = bf2f4(*(const us4*)&sR2[crow * STH + k0]);
        f4 wv = *(const f4*)&co_w[cn * 128 + k0];
        acc = fmaf(hv.x, wv.x, acc);
        acc = fmaf(hv.y, wv.y, acc);
        acc = fmaf(hv.z, wv.z, acc);
        acc = fmaf(hv.w, wv.w, acc);
      }
      float lv = __shfl(acc, lane + 4, 64);  // partner lane holds logvar
      if (cn < 4) {
        float stdv = __expf(0.5f * lv);
        float ov = fmaf(stdv, eps[(size_t)(rbase + crow) * 4 + cn], acc);
        sR2[crow * STH + 128 + cn] = f2bf(acc);
        sR2[crow * STH + 132 + cn] = f2bf(stdv);
        sR3[crow * STR3 + cn] = f2bf(ov);
      }
    }
  }
  __syncthreads();  // B4

  // ---------------- ph5: flush out[:,200:336) from sR2 (coalesced span)
  for (int idx = tid; idx < 128 * 34; idx += NT) {
    int r = idx / 34, c4 = (idx - (idx / 34) * 34) << 2;
    f4 v = bf2f4(*(const us4*)&sR2[r * STH + c4]);
    *(f4*)&out[(size_t)(rbase + r) * HD + 200 + c4] = v;
  }
  __syncthreads();  // B5 (sR2 dead; sGn region live from here)

  // ---------------- ph6: gen GRU (13 col-tiles over 8 waves)
  {  // zero sGn K-pad cols 200..216
    int r = tid >> 2, q = (tid & 3) << 2;
    us4 z = {0, 0, 0, 0};
    *(us4*)&sGn[r * STG + 200 + q] = z;
  }
  {
    const ushort_t* W3 = ws + WS_W3;
    const ushort_t* W4 = ws + WS_W4;
    for (int t = w; t < 13; t += 8) {
      int c = (t << 4) + bn;  // output column (valid < 200)
      bf8 w3f[3], w4a[4][3];
      w3f[0] = *(const bf8*)&W3[(size_t)(c) * 32 + kq];
      w3f[1] = *(const bf8*)&W3[(size_t)(200 + c) * 32 + kq];
      w3f[2] = *(const bf8*)&W3[(size_t)(400 + c) * 32 + kq];
      #pragma unroll
      for (int k = 0; k < 4; ++k) {
        w4a[k][0] = *(const bf8*)&W4[(size_t)(c) * 224 + k * 32 + kq];
        w4a[k][1] = *(const bf8*)&W4[(size_t)(200 + c) * 224 + k * 32 + kq];
        w4a[k][2] = *(const bf8*)&W4[(size_t)(400 + c) * 224 + k * 32 + kq];
      }
      f4 gR[8], gZ[8], gN[8], gHN[8];
      #pragma unroll
      for (int ri = 0; ri < 8; ++ri) {
        gR[ri] = (f4){0.f, 0.f, 0.f, 0.f};
        gZ[ri] = (f4){0.f, 0.f, 0.f, 0.f};
        gN[ri] = (f4){0.f, 0.f, 0.f, 0.f};
        gHN[ri] = (f4){0.f, 0.f, 0.f, 0.f};
      }
      #pragma unroll
      for (int ri = 0; ri < 8; ++ri) {  // gi (K=32)
        bf8 a = *(const bf8*)&sR3[(ri * 16 + bn) * STR3 + kq];
        gR[ri] = MFMA(a, w3f[0], gR[ri]);
        gZ[ri] = MFMA(a, w3f[1], gZ[ri]);
        gN[ri] = MFMA(a, w3f[2], gN[ri]);
      }
      bf8 w4b[3][3];
      #pragma unroll
      for (int k = 0; k < 3; ++k) {
        w4b[k][0] = *(const bf8*)&W4[(size_t)(c) * 224 + (k + 4) * 32 + kq];
        w4b[k][1] = *(const bf8*)&W4[(size_t)(200 + c) * 224 + (k + 4) * 32 + kq];
        w4b[k][2] = *(const bf8*)&W4[(size_t)(400 + c) * 224 + (k + 4) * 32 + kq];
      }
      #pragma unroll
      for (int k = 0; k < 4; ++k) {  // gh batch A
        #pragma unroll
        for (int ri = 0; ri < 8; ++ri) {
          bf8 a = *(const bf8*)&sGo[(ri * 16 + bn) * STG + k * 32 + kq];
          gR[ri] = MFMA(a, w4a[k][0], gR[ri]);
          gZ[ri] = MFMA(a, w4a[k][1], gZ[ri]);
          gHN[ri] = MFMA(a, w4a[k][2], gHN[ri]);
        }
      }
      #pragma unroll
      for (int k = 0; k < 3; ++k) {  // gh batch B
        #pragma unroll
        for (int ri = 0; ri < 8; ++ri) {
          bf8 a = *(const bf8*)&sGo[(ri * 16 + bn) * STG + (k + 4) * 32 + kq];
          gR[ri] = MFMA(a, w4b[k][0], gR[ri]);
          gZ[ri] = MFMA(a, w4b[k][1], gZ[ri]);
          gHN[ri] = MFMA(a, w4b[k][2], gHN[ri]);
        }
      }
      if (c < 200) {
        float brr = gen_b_ih[c] + gen_b_hh[c];
        float brz = gen_b_ih[200 + c] + gen_b_hh[200 + c];
        float bin = gen_b_ih[400 + c], bhn = gen_b_hh[400 + c];
        #pragma unroll
        for (int ri = 0; ri < 8; ++ri) {
          #pragma unroll
          for (int j = 0; j < 4; ++j) {
            int row = ri * 16 + qrow + j;
            float hold = bf2f(sGo[row * STG + c]);
            float rr = sigf(gR[ri][j] + brr);
            float zz = sigf(gZ[ri][j] + brz);
            float nn = tanhf_(gN[ri][j] + bin + rr * (gHN[ri][j] + bhn));
            float hv = (1.f - zz) * nn + zz * hold;
            hv = fminf(fmaxf(hv, -5.f), 5.f);
            sGn[row * STG + c] = f2bf(hv);
          }
        }
      }
    }
  }
  __syncthreads();  // B6

  // ---------------- ph7: factor = gen_state_new @ normed_fac^T -> sR3[20:84)
  {
    const ushort_t* W5 = ws + WS_W5;
    #pragma unroll
    for (int job = 0; job < 4; ++job) {
      int ri = ((w & 3) << 1) + (job & 1);      // 0..7
      int ct = ((w >> 2) << 1) + (job >> 1);    // 0..3
      bf8 w5f[7];
      #pragma unroll
      for (int k = 0; k < 7; ++k)
        w5f[k] = *(const bf8*)&W5[(size_t)((ct << 4) + bn) * 224 + k * 32 + kq];
      f4 acc = (f4){0.f, 0.f, 0.f, 0.f};
      #pragma unroll
      for (int k = 0; k < 7; ++k) {
        bf8 a = *(const bf8*)&sGn[(ri * 16 + bn) * STG + k * 32 + kq];
        acc = MFMA(a, w5f[k], acc);
      }
      #pragma unroll
      for (int j = 0; j < 4; ++j) {
        int row = ri * 16 + qrow + j;
        sR3[row * STR3 + 20 + (ct << 4) + bn] = f2bf(acc[j]);
      }
    }
  }
  __syncthreads();  // B7

  // ---------------- ph8: final flush out[:,0:200) + out[:,336:420)
  for (int idx = tid; idx < 128 * 71; idx += NT) {
    int r = idx / 71, u = idx - (idx / 71) * 71;
    if (u < 50) {
      f4 v = bf2f4(*(const us4*)&sGn[r * STG + (u << 2)]);
      *(f4*)&out[(size_t)(rbase + r) * HD + (u << 2)] = v;
    } else {
      int u2 = u - 50;
      f4 v = bf2f4(*(const us4*)&sR3[r * STR3 + (u2 << 2)]);
      *(f4*)&out[(size_t)(rbase + r) * HD + 336 + (u2 << 2)] = v;
    }
  }
}

extern "C" void kernel_launch(void* const* d_in, const int* in_sizes, int n_in,
                              void* d_out, int out_size, void* d_ws, size_t ws_size,
                              hipStream_t stream) {
  const float* x        = (const float*)d_in[0];
  const float* h0       = (const float*)d_in[1];
  const float* eps      = (const float*)d_in[2];
  const float* gen_w_ih = (const float*)d_in[3];
  const float* gen_w_hh = (const float*)d_in[4];
  const float* gen_b_ih = (const float*)d_in[5];
  const float* gen_b_hh = (const float*)d_in[6];
  const float* con_w_ih = (const float*)d_in[7];
  const float* con_w_hh = (const float*)d_in[8];
  const float* con_b_ih = (const float*)d_in[9];
  const float* con_b_hh = (const float*)d_in[10];
  const float* co_w     = (const float*)d_in[11];
  const float* co_b     = (const float*)d_in[12];
  const float* fac_w    = (const float*)d_in[13];
  float* out = (float*)d_out;
  ushort_t* ws = (ushort_t*)d_ws;

  hipLaunchKernelGGL(prep_w, dim3(256), dim3(512), 0, stream,
                     con_w_ih, con_w_hh, gen_w_ih, gen_w_hh, ws);
  hipLaunchKernelGGL(prep_fac, dim3(64), dim3(64), 0, stream, fac_w, ws);

  int nrows = in_sizes[2] / 4;  // eps is (B,4)
  int grid = nrows / RT;        // 512
  hipLaunchKernelGGL(decoder_kernel, dim3(grid), dim3(NT), 0, stream,
                     x, h0, eps, gen_b_ih, gen_b_hh, con_b_ih, con_b_hh,
                     co_w, co_b, ws, out);
}

// Round 9
// 154.477 us; speedup vs baseline: 1.3771x; 1.1387x over previous
//
#include <hip/hip_runtime.h>
#include <math.h>

// DecoderCell fused kernel — Round 9: R7 structure (RT=128/NT=512), single
// isolated change vs R7: sigmoid/tanh via v_rcp_f32 (__builtin_amdgcn_rcpf)
// instead of IEEE divide (~10-op sequence, 3 per GRU output, 96 outputs per
// thread). R8's inline-asm cvt_pk reverted (NaN source) — conversions back
// to the proven bit-trick.

#define NT 512
#define RT 128
#define XD 272
#define HD 420

typedef unsigned short ushort_t;
typedef __attribute__((ext_vector_type(8))) short bf8;
typedef __attribute__((ext_vector_type(4))) float f4;
typedef __attribute__((ext_vector_type(4))) unsigned short us4;

// ws layout (bf16 element offsets)
#define WS_W1 0         // con_w_ih [384][320]
#define WS_W2 122880    // con_w_hh [384][128]
#define WS_W3 172032    // gen_w_ih [608][32]  (K 20->32 pad, rows 600-607 zero)
#define WS_W4 191488    // gen_w_hh [608][224] (K 200->224 pad, rows 600-607 zero)
#define WS_W5 327680    // normed fac_w [64][224] (K pad zero)

#define STA 328
#define STG 216
#define STH 136
#define STR3 88

#define O_A   0        // sA [128][328] = 83,968 ; later sGo [128][216]=55,296
#define O_GN  55296    // sGn [128][216] = 55,296
#define O_R2  83968    // sR2 [128][136] = 34,816
#define O_R3  118784   // sR3 [128][88]  = 22,528
#define POOLB 141312

__device__ __forceinline__ ushort_t f2bf(float f) {
  union { float f; unsigned u; } v; v.f = f;
  unsigned r = v.u + 0x7FFFu + ((v.u >> 16) & 1u);
  return (ushort_t)(r >> 16);
}
__device__ __forceinline__ float bf2f(ushort_t u) {
  union { unsigned u; float f; } v; v.u = ((unsigned)u) << 16; return v.f;
}
__device__ __forceinline__ us4 f2bf4(f4 v) {
  us4 b; b.x = f2bf(v.x); b.y = f2bf(v.y); b.z = f2bf(v.z); b.w = f2bf(v.w); return b;
}
__device__ __forceinline__ f4 bf2f4(us4 b) {
  f4 v; v.x = bf2f(b.x); v.y = bf2f(b.y); v.z = bf2f(b.z); v.w = bf2f(b.w); return v;
}
__device__ __forceinline__ float rcpf(float x) { return __builtin_amdgcn_rcpf(x); }
__device__ __forceinline__ float sigf(float x) {
  return rcpf(1.0f + __expf(-x));
}
__device__ __forceinline__ float tanhf_(float x) {
  return 1.0f - 2.0f * rcpf(1.0f + __expf(2.0f * x));
}

#define MFMA(a, b, c) __builtin_amdgcn_mfma_f32_16x16x32_bf16((a), (b), (c), 0, 0, 0)

__global__ void prep_w(const float* __restrict__ cw1, const float* __restrict__ cw2,
                       const float* __restrict__ gw3, const float* __restrict__ gw4,
                       ushort_t* __restrict__ ws) {
  int tid = blockIdx.x * blockDim.x + threadIdx.x;
  int np = gridDim.x * blockDim.x;
  for (int i = tid; i < 384 * 320; i += np) ws[WS_W1 + i] = f2bf(cw1[i]);
  for (int i = tid; i < 384 * 128; i += np) ws[WS_W2 + i] = f2bf(cw2[i]);
  for (int i = tid; i < 608 * 32; i += np) {
    int n = i >> 5, k = i & 31;
    ws[WS_W3 + i] = (n < 600 && k < 20) ? f2bf(gw3[n * 20 + k]) : (ushort_t)0;
  }
  for (int i = tid; i < 608 * 224; i += np) {
    int n = i / 224, k = i - n * 224;
    ws[WS_W4 + i] = (n < 600 && k < 200) ? f2bf(gw4[n * 200 + k]) : (ushort_t)0;
  }
}

__global__ void prep_fac(const float* __restrict__ fw, ushort_t* __restrict__ ws) {
  int n = blockIdx.x;   // 64 rows
  int l = threadIdx.x;  // 64 lanes
  float ss = 0.f;
  for (int k = l; k < 200; k += 64) { float v = fw[n * 200 + k]; ss = fmaf(v, v, ss); }
  for (int off = 32; off; off >>= 1) ss += __shfl_down(ss, off, 64);
  ss = __shfl(ss, 0, 64);
  float inv = 1.0f / fmaxf(sqrtf(ss), 1e-12f);
  for (int k = l; k < 224; k += 64)
    ws[WS_W5 + n * 224 + k] = (k < 200) ? f2bf(fw[n * 200 + k] * inv) : (ushort_t)0;
}

__global__ __launch_bounds__(NT, 2) void decoder_kernel(
    const float* __restrict__ x, const float* __restrict__ h0, const float* __restrict__ eps,
    const float* __restrict__ gen_b_ih, const float* __restrict__ gen_b_hh,
    const float* __restrict__ con_b_ih, const float* __restrict__ con_b_hh,
    const float* __restrict__ co_w, const float* __restrict__ co_b,
    const ushort_t* __restrict__ ws, float* __restrict__ out)
{
  __shared__ __align__(16) unsigned char spool[POOLB];
  ushort_t* sA  = (ushort_t*)(spool + O_A);    // con_input [128][328]
  ushort_t* sGo = (ushort_t*)(spool + O_A);    // gen_state_old [128][216]
  ushort_t* sGn = (ushort_t*)(spool + O_GN);   // gen_state_new [128][216]
  ushort_t* sR2 = (ushort_t*)(spool + O_R2);   // con_state(128)+mean(4)+std(4)
  ushort_t* sR3 = (ushort_t*)(spool + O_R3);   // gen_input(20+12p)+factor(64)

  const int tid = threadIdx.x;
  const int rbase = blockIdx.x * RT;
  const int lane = tid & 63;
  const int w = tid >> 6;
  const int bn = lane & 15;           // frag row/col within 16
  const int kq = (lane >> 4) << 3;    // k offset of quarter-wave
  const int qrow = (lane >> 4) << 2;  // C/D row offset of quarter-wave

  // ---------------- ph1: stage con_input, con_state, factor, ext
  #pragma unroll
  for (int it = 0; it < 16; ++it) {  // x[:,0:256] -> sA
    int idx = tid + it * NT;
    int r = idx >> 6, c4 = (idx & 63) << 2;
    f4 v = *(const f4*)&x[(size_t)(rbase + r) * XD + c4];
    *(us4*)&sA[r * STA + c4] = f2bf4(v);
  }
  {  // x[:,256:272] -> sR3 cols 4..20 (gen_input ext)
    int r = tid >> 2, e = (tid & 3) << 2;
    f4 v = *(const f4*)&x[(size_t)(rbase + r) * XD + 256 + e];
    *(us4*)&sR3[r * STR3 + 4 + e] = f2bf4(v);
  }
  #pragma unroll
  for (int it = 0; it < 8; ++it) {  // h0[:,200:328] -> sR2 (con_state_old)
    int idx = tid + it * NT;
    int r = idx >> 5, c4 = (idx & 31) << 2;
    f4 v = *(const f4*)&h0[(size_t)(rbase + r) * HD + 200 + c4];
    *(us4*)&sR2[r * STH + c4] = f2bf4(v);
  }
  #pragma unroll
  for (int it = 0; it < 4; ++it) {  // h0[:,356:420] -> sA cols 256..320
    int idx = tid + it * NT;
    int r = idx >> 4, c4 = (idx & 15) << 2;
    f4 v = *(const f4*)&h0[(size_t)(rbase + r) * HD + 356 + c4];
    *(us4*)&sA[r * STA + 256 + c4] = f2bf4(v);
  }
  if (tid < 384) {  // zero sR3 cols 20..32 (gi K-pad)
    int r = tid / 3, q = (tid - (tid / 3) * 3) << 2;
    us4 z = {0, 0, 0, 0};
    *(us4*)&sR3[r * STR3 + 20 + q] = z;
  }
  __syncthreads();  // B1

  const int col = (w << 4) + bn;  // wave's con output column (0..127)

  // ---------------- ph2: con GEMMs (8 row-tiles/wave), batched prefetch
  f4 aR[8], aZ[8], aN[8], aHN[8];
  #pragma unroll
  for (int ri = 0; ri < 8; ++ri) {
    aR[ri] = (f4){0.f, 0.f, 0.f, 0.f};
    aZ[ri] = (f4){0.f, 0.f, 0.f, 0.f};
    aN[ri] = (f4){0.f, 0.f, 0.f, 0.f};
    aHN[ri] = (f4){0.f, 0.f, 0.f, 0.f};
  }
  {
    const ushort_t* W2 = ws + WS_W2;
    const ushort_t* W1 = ws + WS_W1;
    bf8 w2f[4][3], w1a[5][3];
    #pragma unroll
    for (int k = 0; k < 4; ++k) {
      w2f[k][0] = *(const bf8*)&W2[(size_t)(col) * 128 + k * 32 + kq];
      w2f[k][1] = *(const bf8*)&W2[(size_t)(128 + col) * 128 + k * 32 + kq];
      w2f[k][2] = *(const bf8*)&W2[(size_t)(256 + col) * 128 + k * 32 + kq];
    }
    #pragma unroll
    for (int k = 0; k < 5; ++k) {
      w1a[k][0] = *(const bf8*)&W1[(size_t)(col) * 320 + k * 32 + kq];
      w1a[k][1] = *(const bf8*)&W1[(size_t)(128 + col) * 320 + k * 32 + kq];
      w1a[k][2] = *(const bf8*)&W1[(size_t)(256 + col) * 320 + k * 32 + kq];
    }
    #pragma unroll
    for (int k = 0; k < 4; ++k) {  // gh (K=128)
      #pragma unroll
      for (int ri = 0; ri < 8; ++ri) {
        bf8 a = *(const bf8*)&sR2[(ri * 16 + bn) * STH + k * 32 + kq];
        aR[ri] = MFMA(a, w2f[k][0], aR[ri]);
        aZ[ri] = MFMA(a, w2f[k][1], aZ[ri]);
        aHN[ri] = MFMA(a, w2f[k][2], aHN[ri]);
      }
    }
    bf8 w1b[5][3];
    #pragma unroll
    for (int k = 0; k < 5; ++k) {
      w1b[k][0] = *(const bf8*)&W1[(size_t)(col) * 320 + (k + 5) * 32 + kq];
      w1b[k][1] = *(const bf8*)&W1[(size_t)(128 + col) * 320 + (k + 5) * 32 + kq];
      w1b[k][2] = *(const bf8*)&W1[(size_t)(256 + col) * 320 + (k + 5) * 32 + kq];
    }
    #pragma unroll
    for (int k = 0; k < 5; ++k) {  // gi batch A
      #pragma unroll
      for (int ri = 0; ri < 8; ++ri) {
        bf8 a = *(const bf8*)&sA[(ri * 16 + bn) * STA + k * 32 + kq];
        aR[ri] = MFMA(a, w1a[k][0], aR[ri]);
        aZ[ri] = MFMA(a, w1a[k][1], aZ[ri]);
        aN[ri] = MFMA(a, w1a[k][2], aN[ri]);
      }
    }
    #pragma unroll
    for (int k = 0; k < 5; ++k) {  // gi batch B
      #pragma unroll
      for (int ri = 0; ri < 8; ++ri) {
        bf8 a = *(const bf8*)&sA[(ri * 16 + bn) * STA + (k + 5) * 32 + kq];
        aR[ri] = MFMA(a, w1b[k][0], aR[ri]);
        aZ[ri] = MFMA(a, w1b[k][1], aZ[ri]);
        aN[ri] = MFMA(a, w1b[k][2], aN[ri]);
      }
    }
  }
  __syncthreads();  // B2 (sA + sR2 frag reads done)

  // ---------------- ph3: stage gen_state_old (over dead sA) || elementwise
  for (int idx = tid; idx < 128 * 54; idx += NT) {
    int r = idx / 54, u = idx - (idx / 54) * 54;
    if (u < 50) {
      f4 v = *(const f4*)&h0[(size_t)(rbase + r) * HD + (u << 2)];
      *(us4*)&sGo[r * STG + (u << 2)] = f2bf4(v);
    } else {
      us4 z = {0, 0, 0, 0};
      *(us4*)&sGo[r * STG + 200 + ((u - 50) << 2)] = z;  // gh K-pad
    }
  }
  {
    float brr = con_b_ih[col] + con_b_hh[col];
    float brz = con_b_ih[128 + col] + con_b_hh[128 + col];
    float bin = con_b_ih[256 + col], bhn = con_b_hh[256 + col];
    #pragma unroll
    for (int ri = 0; ri < 8; ++ri) {
      #pragma unroll
      for (int j = 0; j < 4; ++j) {
        int row = ri * 16 + qrow + j;
        float hold = bf2f(sR2[row * STH + col]);
        float rr = sigf(aR[ri][j] + brr);
        float zz = sigf(aZ[ri][j] + brz);
        float nn = tanhf_(aN[ri][j] + bin + rr * (aHN[ri][j] + bhn));
        float hv = (1.f - zz) * nn + zz * hold;
        hv = fminf(fmaxf(hv, -5.f), 5.f);
        sR2[row * STH + col] = f2bf(hv);  // own (row,col) only: no race
      }
    }
  }
  __syncthreads();  // B3

  // ---------------- ph4: co linear + reparam (f32 VALU; 128 rows x 8 cols)
  {
    int cn = tid & 7;
    #pragma unroll
    for (int half = 0; half < 2; ++half) {
      int crow = (tid >> 3) + half * 64;
      float acc = co_b[cn];
      #pragma unroll 8
      for (int k0 = 0; k0 < 128; k0 += 4) {
        f4 hv = bf2f4(*(const us4*)&sR2[crow * STH + k0]);
        f4 wv = *(const f4*)&co_w[cn * 128 + k0];
        acc = fmaf(hv.x, wv.x, acc);
        acc = fmaf(hv.y, wv.y, acc);
        acc = fmaf(hv.z, wv.z, acc);
        acc = fmaf(hv.w, wv.w, acc);
      }
      float lv = __shfl(acc, lane + 4, 64);  // partner lane holds logvar
      if (cn < 4) {
        float stdv = __expf(0.5f * lv);
        float ov = fmaf(stdv, eps[(size_t)(rbase + crow) * 4 + cn], acc);
        sR2[crow * STH + 128 + cn] = f2bf(acc);
        sR2[crow * STH + 132 + cn] = f2bf(stdv);
        sR3[crow * STR3 + cn] = f2bf(ov);
      }
    }
  }
  __syncthreads();  // B4

  // ---------------- ph5: flush out[:,200:336) from sR2 (coalesced span)
  for (int idx = tid; idx < 128 * 34; idx += NT) {
    int r = idx / 34, c4 = (idx - (idx / 34) * 34) << 2;
    f4 v = bf2f4(*(const us4*)&sR2[r * STH + c4]);
    *(f4*)&out[(size_t)(rbase + r) * HD + 200 + c4] = v;
  }
  __syncthreads();  // B5 (sR2 dead; sGn region live from here)

  // ---------------- ph6: gen GRU (13 col-tiles over 8 waves)
  {  // zero sGn K-pad cols 200..216
    int r = tid >> 2, q = (tid & 3) << 2;
    us4 z = {0, 0, 0, 0};
    *(us4*)&sGn[r * STG + 200 + q] = z;
  }
  {
    const ushort_t* W3 = ws + WS_W3;
    const ushort_t* W4 = ws + WS_W4;
    for (int t = w; t < 13; t += 8) {
      int c = (t << 4) + bn;  // output column (valid < 200)
      bf8 w3f[3], w4a[4][3];
      w3f[0] = *(const bf8*)&W3[(size_t)(c) * 32 + kq];
      w3f[1] = *(const bf8*)&W3[(size_t)(200 + c) * 32 + kq];
      w3f[2] = *(const bf8*)&W3[(size_t)(400 + c) * 32 + kq];
      #pragma unroll
      for (int k = 0; k < 4; ++k) {
        w4a[k][0] = *(const bf8*)&W4[(size_t)(c) * 224 + k * 32 + kq];
        w4a[k][1] = *(const bf8*)&W4[(size_t)(200 + c) * 224 + k * 32 + kq];
        w4a[k][2] = *(const bf8*)&W4[(size_t)(400 + c) * 224 + k * 32 + kq];
      }
      f4 gR[8], gZ[8], gN[8], gHN[8];
      #pragma unroll
      for (int ri = 0; ri < 8; ++ri) {
        gR[ri] = (f4){0.f, 0.f, 0.f, 0.f};
        gZ[ri] = (f4){0.f, 0.f, 0.f, 0.f};
        gN[ri] = (f4){0.f, 0.f, 0.f, 0.f};
        gHN[ri] = (f4){0.f, 0.f, 0.f, 0.f};
      }
      #pragma unroll
      for (int ri = 0; ri < 8; ++ri) {  // gi (K=32)
        bf8 a = *(const bf8*)&sR3[(ri * 16 + bn) * STR3 + kq];
        gR[ri] = MFMA(a, w3f[0], gR[ri]);
        gZ[ri] = MFMA(a, w3f[1], gZ[ri]);
        gN[ri] = MFMA(a, w3f[2], gN[ri]);
      }
      bf8 w4b[3][3];
      #pragma unroll
      for (int k = 0; k < 3; ++k) {
        w4b[k][0] = *(const bf8*)&W4[(size_t)(c) * 224 + (k + 4) * 32 + kq];
        w4b[k][1] = *(const bf8*)&W4[(size_t)(200 + c) * 224 + (k + 4) * 32 + kq];
        w4b[k][2] = *(const bf8*)&W4[(size_t)(400 + c) * 224 + (k + 4) * 32 + kq];
      }
      #pragma unroll
      for (int k = 0; k < 4; ++k) {  // gh batch A
        #pragma unroll
        for (int ri = 0; ri < 8; ++ri) {
          bf8 a = *(const bf8*)&sGo[(ri * 16 + bn) * STG + k * 32 + kq];
          gR[ri] = MFMA(a, w4a[k][0], gR[ri]);
          gZ[ri] = MFMA(a, w4a[k][1], gZ[ri]);
          gHN[ri] = MFMA(a, w4a[k][2], gHN[ri]);
        }
      }
      #pragma unroll
      for (int k = 0; k < 3; ++k) {  // gh batch B
        #pragma unroll
        for (int ri = 0; ri < 8; ++ri) {
          bf8 a = *(const bf8*)&sGo[(ri * 16 + bn) * STG + (k + 4) * 32 + kq];
          gR[ri] = MFMA(a, w4b[k][0], gR[ri]);
          gZ[ri] = MFMA(a, w4b[k][1], gZ[ri]);
          gHN[ri] = MFMA(a, w4b[k][2], gHN[ri]);
        }
      }
      if (c < 200) {
        float brr = gen_b_ih[c] + gen_b_hh[c];
        float brz = gen_b_ih[200 + c] + gen_b_hh[200 + c];
        float bin = gen_b_ih[400 + c], bhn = gen_b_hh[400 + c];
        #pragma unroll
        for (int ri = 0; ri < 8; ++ri) {
          #pragma unroll
          for (int j = 0; j < 4; ++j) {
            int row = ri * 16 + qrow + j;
            float hold = bf2f(sGo[row * STG + c]);
            float rr = sigf(gR[ri][j] + brr);
            float zz = sigf(gZ[ri][j] + brz);
            float nn = tanhf_(gN[ri][j] + bin + rr * (gHN[ri][j] + bhn));
            float hv = (1.f - zz) * nn + zz * hold;
            hv = fminf(fmaxf(hv, -5.f), 5.f);
            sGn[row * STG + c] = f2bf(hv);
          }
        }
      }
    }
  }
  __syncthreads();  // B6

  // ---------------- ph7: factor = gen_state_new @ normed_fac^T -> sR3[20:84)
  {
    const ushort_t* W5 = ws + WS_W5;
    #pragma unroll
    for (int job = 0; job < 4; ++job) {
      int ri = ((w & 3) << 1) + (job & 1);      // 0..7
      int ct = ((w >> 2) << 1) + (job >> 1);    // 0..3
      bf8 w5f[7];
      #pragma unroll
      for (int k = 0; k < 7; ++k)
        w5f[k] = *(const bf8*)&W5[(size_t)((ct << 4) + bn) * 224 + k * 32 + kq];
      f4 acc = (f4){0.f, 0.f, 0.f, 0.f};
      #pragma unroll
      for (int k = 0; k < 7; ++k) {
        bf8 a = *(const bf8*)&sGn[(ri * 16 + bn) * STG + k * 32 + kq];
        acc = MFMA(a, w5f[k], acc);
      }
      #pragma unroll
      for (int j = 0; j < 4; ++j) {
        int row = ri * 16 + qrow + j;
        sR3[row * STR3 + 20 + (ct << 4) + bn] = f2bf(acc[j]);
      }
    }
  }
  __syncthreads();  // B7

  // ---------------- ph8: final flush out[:,0:200) + out[:,336:420)
  for (int idx = tid; idx < 128 * 71; idx += NT) {
    int r = idx / 71, u = idx - (idx / 71) * 71;
    if (u < 50) {
      f4 v = bf2f4(*(const us4*)&sGn[r * STG + (u << 2)]);
      *(f4*)&out[(size_t)(rbase + r) * HD + (u << 2)] = v;
    } else {
      int u2 = u - 50;
      f4 v = bf2f4(*(const us4*)&sR3[r * STR3 + (u2 << 2)]);
      *(f4*)&out[(size_t)(rbase + r) * HD + 336 + (u2 << 2)] = v;
    }
  }
}

extern "C" void kernel_launch(void* const* d_in, const int* in_sizes, int n_in,
                              void* d_out, int out_size, void* d_ws, size_t ws_size,
                              hipStream_t stream) {
  const float* x        = (const float*)d_in[0];
  const float* h0       = (const float*)d_in[1];
  const float* eps      = (const float*)d_in[2];
  const float* gen_w_ih = (const float*)d_in[3];
  const float* gen_w_hh = (const float*)d_in[4];
  const float* gen_b_ih = (const float*)d_in[5];
  const float* gen_b_hh = (const float*)d_in[6];
  const float* con_w_ih = (const float*)d_in[7];
  const float* con_w_hh = (const float*)d_in[8];
  const float* con_b_ih = (const float*)d_in[9];
  const float* con_b_hh = (const float*)d_in[10];
  const float* co_w     = (const float*)d_in[11];
  const float* co_b     = (const float*)d_in[12];
  const float* fac_w    = (const float*)d_in[13];
  float* out = (float*)d_out;
  ushort_t* ws = (ushort_t*)d_ws;

  hipLaunchKernelGGL(prep_w, dim3(256), dim3(512), 0, stream,
                     con_w_ih, con_w_hh, gen_w_ih, gen_w_hh, ws);
  hipLaunchKernelGGL(prep_fac, dim3(64), dim3(64), 0, stream, fac_w, ws);

  int nrows = in_sizes[2] / 4;  // eps is (B,4)
  int grid = nrows / RT;        // 512
  hipLaunchKernelGGL(decoder_kernel, dim3(grid), dim3(NT), 0, stream,
                     x, h0, eps, gen_b_ih, gen_b_hh, con_b_ih, con_b_hh,
                     co_w, co_b, ws, out);
}